// Round 12
// baseline (240.008 us; speedup 1.0000x reference)
//
#include <hip/hip_runtime.h>
#include <cstdint>
#include <cstddef>

#define N_NODES 50000
#define N_EDGES 1600000
#define IN_FEAT 512
#define OUT_FEAT 128
#define NEG_SLOPE 0.01f
#define INV_TEMP 2.0f
#define PAD_DEG 128     // P(Poisson(32) >= 128) ~ e^-81: never

// two-phase CSR build
#define BUCKETS 400
#define BNODES 125      // nodes per bucket (400*125 = 50000)
#define BCAP 5000       // bucket capacity; Poisson(4000) max over 400 ~ 4300
#define A_BLOCKS 500
#define A_EPC (N_EDGES / A_BLOCKS)   // 3200 edges per block
#define A_G4 (A_EPC / 4)             // 800 int4 groups

#define CONV_BLOCKS ((IN_FEAT * OUT_FEAT) / 256)   // 256
#define GEMM_BLOCKS ((N_NODES + 127) / 128)        // 391 (tile 128x128, 8 waves)

// binB_node split: 2 half-bucket blocks per bucket
#define HB_LO 63        // nodes in half 0; half 1 gets 62

typedef __attribute__((ext_vector_type(8))) short short8;
typedef __attribute__((ext_vector_type(4))) float f32x4;

#define GLOBAL_AS __attribute__((address_space(1)))
#define LDS_AS __attribute__((address_space(3)))

__device__ inline unsigned short f2bf(float x) {
    unsigned int u = __float_as_uint(x);
    unsigned int r = (u + 0x7fffu + ((u >> 16) & 1u)) >> 16;
    return (unsigned short)r;
}
__device__ inline float bf2f(unsigned short b) {
    return __uint_as_float(((unsigned int)b) << 16);
}

// ---------------- K1: convert_w + zero bucket cursors ----------------

__global__ __launch_bounds__(256) void convw_kernel(const float* __restrict__ W,
                                                    unsigned short* __restrict__ Wt,
                                                    int* __restrict__ bucket_cursor) {
    int tid = blockIdx.x * 256 + threadIdx.x;
    if (tid < BUCKETS) bucket_cursor[tid] = 0;
    if (tid < IN_FEAT * OUT_FEAT) {
        int n = tid >> 9;
        int k = tid & 511;
        Wt[tid] = f2bf(W[k * OUT_FEAT + n]);
    }
}

// ---------------- K2: fused {mfma_gemm, binA} (proven: ~60us) ----------------

__global__ __launch_bounds__(512) void gemm_binA_kernel(const float* __restrict__ h,
                                                        const unsigned short* __restrict__ Wt,
                                                        const float* __restrict__ a_vec,
                                                        unsigned short* __restrict__ Whb,
                                                        float* __restrict__ s1,
                                                        float* __restrict__ s2,
                                                        const int* __restrict__ src,
                                                        const int* __restrict__ dst,
                                                        int* __restrict__ bucket_cursor,
                                                        int* __restrict__ binned) {
    __shared__ unsigned short lB[3][8 * 2 * 64 * 8];   // 48 KB (gemm); binA aliases front 3.2KB

    if (blockIdx.x >= GEMM_BLOCKS) {
        // ---- binA role: bin edges by bucket (512-thread strides)
        int* cntL = (int*)&lB[0][0];
        int* baseL = cntL + BUCKETS;
        int t = threadIdx.x;
        for (int i = t; i < BUCKETS; i += 512) cntL[i] = 0;
        __syncthreads();
        size_t ebase = (size_t)(blockIdx.x - GEMM_BLOCKS) * A_EPC;

        for (int g = t; g < A_G4; g += 512) {
            int4 s4 = *(const int4*)(src + ebase + (size_t)g * 4);
#pragma unroll
            for (int j = 0; j < 4; ++j) {
                int s = (&s4.x)[j];
                atomicAdd(&cntL[s / BNODES], 1);
            }
        }
        __syncthreads();
        for (int i = t; i < BUCKETS; i += 512) {
            int c = cntL[i];
            baseL[i] = c ? atomicAdd(&bucket_cursor[i], c) : 0;
            cntL[i] = 0;
        }
        __syncthreads();
        for (int g = t; g < A_G4; g += 512) {
            int4 s4 = *(const int4*)(src + ebase + (size_t)g * 4);
            int4 d4 = *(const int4*)(dst + ebase + (size_t)g * 4);
#pragma unroll
            for (int j = 0; j < 4; ++j) {
                int s = (&s4.x)[j];
                int b = s / BNODES;
                int sl = s - b * BNODES;
                int pos = atomicAdd(&cntL[b], 1);
                int slot = baseL[b] + pos;
                if (slot < BCAP)
                    binned[(size_t)b * BCAP + slot] = (sl << 16) | (&d4.x)[j];
            }
        }
        return;
    }

    // ---- gemm role: tile 128x128, 8 waves (16 rows each), BK=64
    int bid = blockIdx.x;
    int t = threadIdx.x;
    int w = t >> 6;          // 0..7
    int L = t & 63;
    int m0 = bid * 128;

    int arow = m0 + w * 16 + (L & 15);
    int arow_c = arow < N_NODES ? arow : N_NODES - 1;   // clamp: loads unconditional
    int kq = (L >> 4) * 8;
    const float* arp = h + (size_t)arow_c * IN_FEAT + kq;

    f32x4 acc[8];
#pragma unroll
    for (int i = 0; i < 8; ++i) acc[i] = (f32x4){0.f, 0.f, 0.f, 0.f};

    auto stageB = [&](int slot, int k0) {
#pragma unroll
        for (int ksub = 0; ksub < 2; ++ksub) {
            const GLOBAL_AS unsigned short* g =
                (const GLOBAL_AS unsigned short*)(Wt + (size_t)(w * 16 + (L & 15)) * IN_FEAT +
                                                  (k0 + ksub * 32 + kq));
            LDS_AS unsigned short* lp = (LDS_AS unsigned short*)(&lB[slot][(w * 2 + ksub) * 512]);
            __builtin_amdgcn_global_load_lds((const GLOBAL_AS void*)g, (LDS_AS void*)lp, 16, 0, 0);
        }
    };
    auto loadA = [&](int step, float4 out[4]) {
        const float* p = arp + step * 64;
        out[0] = *(const float4*)(p);
        out[1] = *(const float4*)(p + 4);
        out[2] = *(const float4*)(p + 32);
        out[3] = *(const float4*)(p + 36);
    };
    auto convA = [&](const float4 a[4], short8& f0, short8& f1) {
        short8 v;
        v[0] = (short)f2bf(a[0].x); v[1] = (short)f2bf(a[0].y);
        v[2] = (short)f2bf(a[0].z); v[3] = (short)f2bf(a[0].w);
        v[4] = (short)f2bf(a[1].x); v[5] = (short)f2bf(a[1].y);
        v[6] = (short)f2bf(a[1].z); v[7] = (short)f2bf(a[1].w);
        f0 = v;
        v[0] = (short)f2bf(a[2].x); v[1] = (short)f2bf(a[2].y);
        v[2] = (short)f2bf(a[2].z); v[3] = (short)f2bf(a[2].w);
        v[4] = (short)f2bf(a[3].x); v[5] = (short)f2bf(a[3].y);
        v[6] = (short)f2bf(a[3].z); v[7] = (short)f2bf(a[3].w);
        f1 = v;
    };

    float4 avA[4], avB[4], avC[4];
#pragma unroll
    for (int q = 0; q < 4; ++q) avC[q] = make_float4(0.f, 0.f, 0.f, 0.f);

    stageB(0, 0);
    asm volatile("" ::: "memory");   // pin: stage(0) oldest in vmcnt order
    stageB(1, 64);
    loadA(0, avA);
    loadA(1, avB);
    asm volatile("s_waitcnt vmcnt(10)" ::: "memory");
    __builtin_amdgcn_s_barrier();

#pragma unroll
    for (int it = 0; it < 8; ++it) {
        if (it < 6) {
            stageB((it + 2) % 3, (it + 2) * 64);   // 2 VMEM
            loadA(it + 2, avC);                    // 4 VMEM
        }

        short8 af0, af1;
        convA(avA, af0, af1);

        const int buf = it % 3;
#pragma unroll
        for (int nb = 0; nb < 8; ++nb) {
            short8 bf = *(const short8*)(&lB[buf][((nb * 2 + 0) * 64 + L) * 8]);
            acc[nb] = __builtin_amdgcn_mfma_f32_16x16x32_bf16(af0, bf, acc[nb], 0, 0, 0);
        }
#pragma unroll
        for (int nb = 0; nb < 8; ++nb) {
            short8 bf = *(const short8*)(&lB[buf][((nb * 2 + 1) * 64 + L) * 8]);
            acc[nb] = __builtin_amdgcn_mfma_f32_16x16x32_bf16(af1, bf, acc[nb], 0, 0, 0);
        }

#pragma unroll
        for (int q = 0; q < 4; ++q) { avA[q] = avB[q]; avB[q] = avC[q]; }

        if (it < 6) {
            asm volatile("s_waitcnt vmcnt(6)" ::: "memory");
            __builtin_amdgcn_s_barrier();
        } else if (it == 6) {
            asm volatile("s_waitcnt vmcnt(0)" ::: "memory");
            __builtin_amdgcn_s_barrier();
        }
    }

    int col0 = L & 15;
    int rbase = m0 + w * 16 + (L >> 4) * 4;

    float a1c[8], a2c[8];
#pragma unroll
    for (int nb = 0; nb < 8; ++nb) {
        a1c[nb] = a_vec[nb * 16 + col0];
        a2c[nb] = a_vec[128 + nb * 16 + col0];
    }

#pragma unroll
    for (int r = 0; r < 4; ++r) {
        int row = rbase + r;
        bool ok = row < N_NODES;
        float p1 = 0.f, p2 = 0.f;
        if (ok) {
            unsigned short* orow = Whb + (size_t)row * OUT_FEAT;
#pragma unroll
            for (int nb = 0; nb < 8; ++nb) {
                float v = acc[nb][r];
                orow[nb * 16 + col0] = f2bf(v);
                p1 = fmaf(v, a1c[nb], p1);
                p2 = fmaf(v, a2c[nb], p2);
            }
        }
#pragma unroll
        for (int off = 8; off > 0; off >>= 1) {
            p1 += __shfl_xor(p1, off, 64);
            p2 += __shfl_xor(p2, off, 64);
        }
        if (ok && col0 == 0) {
            s1[row] = p1;
            s2[row] = p2;
        }
    }
}

// ---------------- K3: fused {binB scatter -> LDS CSR, node softmax+agg} ----
// v3: 800 half-bucket blocks x 512 threads. Round-11's 400x1024 grid packed
// only 2 blocks/CU (thread cap) -> 144 CUs ran 2 sequential blocks while
// 112 idled in the tail (makespan ~2x block time). Splitting each bucket
// into two half-bucket blocks (nodes [0,63) / [63,125)) gives: 16KB LDS CSR,
// 4 blocks/CU thread-cap, ~3.1 blocks/CU actual, 32 waves/CU, near-even
// loading. Each half-block scans the full bucket list and keeps its half
// (+12.8MB binned re-read — trivial). Per-wave node body unchanged.

__global__ __launch_bounds__(512) void binB_node_kernel(const unsigned short* __restrict__ Whb,
                                                        const float* __restrict__ s1,
                                                        const float* __restrict__ s2,
                                                        const int* __restrict__ bucket_cursor,
                                                        const int* __restrict__ binned,
                                                        float* __restrict__ out) {
    __shared__ int cL[HB_LO];                                 // 252 B
    __shared__ unsigned short csrL[HB_LO * PAD_DEG];          // 16128 B
    int b = blockIdx.x >> 1;
    int half = blockIdx.x & 1;
    int lo = half ? HB_LO : 0;
    int hi = half ? BNODES : HB_LO;
    int count = hi - lo;
    int t = threadIdx.x;
    int n0 = b * BNODES + lo;

    // ---- phase 1: bucket -> LDS csr (this half only)
    if (t < count) cL[t] = 0;
    __syncthreads();
    int m = min(bucket_cursor[b], BCAP);
    const int* bp = binned + (size_t)b * BCAP;
    for (int i = t; i < m; i += 512) {
        int p = bp[i];
        int sl = p >> 16;
        if (sl >= lo && sl < hi) {
            int d = p & 0xFFFF;
            int pos = atomicAdd(&cL[sl - lo], 1);
            if (pos < PAD_DEG) csrL[(sl - lo) * PAD_DEG + pos] = (unsigned short)d;
        }
    }
    __syncthreads();

    // ---- phase 2: per-node softmax + aggregation (wave w: nodes w, w+8, ...)
    int lane = t & 63;
    int w = t >> 6;          // 0..7
    int g = lane >> 4;
    int fo = lane & 15;

    for (int sl = w; sl < count; sl += 8) {
        int n = n0 + sl;
        int deg = min(cL[sl], PAD_DEG);
        const unsigned short* crow = &csrL[sl * PAD_DEG];

        float accv[8];
#pragma unroll
        for (int f = 0; f < 8; ++f) accv[f] = 0.f;
        float inv = 0.f;

        if (deg > 0) {
            float s1n = s1[n];
            int d0 = 0, d1 = 0;
            float ex0 = 0.f, ex1 = 0.f;
            if (lane < deg) {
                d0 = crow[lane];
                float ev = s1n + s2[d0];
                ev = ev >= 0.f ? ev : NEG_SLOPE * ev;
                ex0 = __expf(ev * INV_TEMP);
            }
            if (lane + 64 < deg) {
                d1 = crow[lane + 64];
                float ev = s1n + s2[d1];
                ev = ev >= 0.f ? ev : NEG_SLOPE * ev;
                ex1 = __expf(ev * INV_TEMP);
            }
            float denom = ex0 + ex1;
#pragma unroll
            for (int off = 32; off > 0; off >>= 1) denom += __shfl_xor(denom, off, 64);
            inv = 1.0f / denom;

#pragma unroll 2
            for (int jj = 0; jj < deg; jj += 8) {
                int e0 = jj + g;
                int e1 = jj + 4 + g;
                bool hi0 = jj >= 64;                 // wave-uniform
                bool hi1 = (jj + 4) >= 64;           // wave-uniform
                float p0 = __shfl(hi0 ? ex1 : ex0, e0 & 63, 64);
                int dd0 = __shfl(hi0 ? d1 : d0, e0 & 63, 64);
                float p1 = __shfl(hi1 ? ex1 : ex0, e1 & 63, 64);
                int dd1 = __shfl(hi1 ? d1 : d0, e1 & 63, 64);
                short8 row0 = *(const short8*)(Whb + (size_t)dd0 * OUT_FEAT + fo * 8);
                short8 row1 = *(const short8*)(Whb + (size_t)dd1 * OUT_FEAT + fo * 8);
#pragma unroll
                for (int f = 0; f < 8; ++f)
                    accv[f] = fmaf(p0, bf2f((unsigned short)row0[f]), accv[f]);
#pragma unroll
                for (int f = 0; f < 8; ++f)
                    accv[f] = fmaf(p1, bf2f((unsigned short)row1[f]), accv[f]);
            }
#pragma unroll
            for (int f = 0; f < 8; ++f) {
                accv[f] += __shfl_xor(accv[f], 16, 64);
                accv[f] += __shfl_xor(accv[f], 32, 64);
            }
        }

        if (g == 0) {
            float* orow = out + (size_t)n * OUT_FEAT + fo * 8;
            float4 o0, o1;
            o0.x = fmaxf(accv[0] * inv, 0.f); o0.y = fmaxf(accv[1] * inv, 0.f);
            o0.z = fmaxf(accv[2] * inv, 0.f); o0.w = fmaxf(accv[3] * inv, 0.f);
            o1.x = fmaxf(accv[4] * inv, 0.f); o1.y = fmaxf(accv[5] * inv, 0.f);
            o1.z = fmaxf(accv[6] * inv, 0.f); o1.w = fmaxf(accv[7] * inv, 0.f);
            *(float4*)(orow) = o0;
            *(float4*)(orow + 4) = o1;
        }
    }
}

// ---------------- launch ----------------

extern "C" void kernel_launch(void* const* d_in, const int* in_sizes, int n_in,
                              void* d_out, int out_size, void* d_ws, size_t ws_size,
                              hipStream_t stream) {
    const float* h = (const float*)d_in[0];
    const float* W = (const float*)d_in[1];
    const float* a = (const float*)d_in[2];
    const int* edge = (const int*)d_in[3];
    const int* src = edge;
    const int* dst = edge + N_EDGES;
    float* out = (float*)d_out;

    char* ws = (char*)d_ws;
    size_t off = 0;
    auto alloc = [&](size_t bytes) -> void* {
        void* p = ws + off;
        off = (off + bytes + 255) & ~(size_t)255;
        return p;
    };
    unsigned short* Whb = (unsigned short*)alloc((size_t)N_NODES * OUT_FEAT * sizeof(unsigned short));
    float* s1 = (float*)alloc((size_t)N_NODES * sizeof(float));
    float* s2 = (float*)alloc((size_t)N_NODES * sizeof(float));
    unsigned short* Wt = (unsigned short*)alloc((size_t)IN_FEAT * OUT_FEAT * sizeof(unsigned short));
    int* bucket_cursor = (int*)alloc((size_t)BUCKETS * sizeof(int));
    int* binned = (int*)alloc((size_t)BUCKETS * BCAP * sizeof(int));

    convw_kernel<<<CONV_BLOCKS, 256, 0, stream>>>(W, Wt, bucket_cursor);
    gemm_binA_kernel<<<GEMM_BLOCKS + A_BLOCKS, 512, 0, stream>>>(h, Wt, a, Whb, s1, s2,
                                                                 src, dst, bucket_cursor, binned);
    binB_node_kernel<<<BUCKETS * 2, 512, 0, stream>>>(Whb, s1, s2, bucket_cursor, binned, out);
}

// Round 13
// 233.241 us; speedup vs baseline: 1.0290x; 1.0290x over previous
//
#include <hip/hip_runtime.h>
#include <cstdint>
#include <cstddef>

#define N_NODES 50000
#define N_EDGES 1600000
#define IN_FEAT 512
#define OUT_FEAT 128
#define NEG_SLOPE 0.01f
#define INV_TEMP 2.0f
#define PAD_DEG 128     // P(Poisson(32) >= 128) ~ e^-81: never

// two-phase CSR build — v13 geometry: 1000 buckets x 50 nodes.
// binB_node gets ~3.9 blocks/CU (balanced) + 2.5x shorter scans without the
// round-12 double-scan; binA LDS counters grow to 8KB (fits in gemm alias).
#define BUCKETS 1000
#define BNODES 50       // nodes per bucket (1000*50 = 50000)
#define BCAP 2000       // Poisson(1600) max over 1000 ~ 1760
#define A_BLOCKS 500
#define A_EPC (N_EDGES / A_BLOCKS)   // 3200 edges per block
#define A_G4 (A_EPC / 4)             // 800 int4 groups

#define CONV_BLOCKS ((IN_FEAT * OUT_FEAT) / 256)   // 256
#define GEMM_BLOCKS ((N_NODES + 127) / 128)        // 391 (tile 128x128, 8 waves)

typedef __attribute__((ext_vector_type(8))) short short8;
typedef __attribute__((ext_vector_type(4))) float f32x4;
typedef __attribute__((ext_vector_type(2))) float f32x2;

#define GLOBAL_AS __attribute__((address_space(1)))
#define LDS_AS __attribute__((address_space(3)))

__device__ inline unsigned short f2bf(float x) {
    unsigned int u = __float_as_uint(x);
    unsigned int r = (u + 0x7fffu + ((u >> 16) & 1u)) >> 16;
    return (unsigned short)r;
}
__device__ inline float bf2f(unsigned short b) {
    return __uint_as_float(((unsigned int)b) << 16);
}

// ---------------- K1: convert_w + zero bucket cursors ----------------

__global__ __launch_bounds__(256) void convw_kernel(const float* __restrict__ W,
                                                    unsigned short* __restrict__ Wt,
                                                    int* __restrict__ bucket_cursor) {
    int tid = blockIdx.x * 256 + threadIdx.x;
    if (tid < BUCKETS) bucket_cursor[tid] = 0;
    if (tid < IN_FEAT * OUT_FEAT) {
        int n = tid >> 9;
        int k = tid & 511;
        Wt[tid] = f2bf(W[k * OUT_FEAT + n]);
    }
}

// ---------------- K2: fused {mfma_gemm, binA} (proven: ~61us) ----------------

__global__ __launch_bounds__(512) void gemm_binA_kernel(const float* __restrict__ h,
                                                        const unsigned short* __restrict__ Wt,
                                                        const float* __restrict__ a_vec,
                                                        unsigned short* __restrict__ Whb,
                                                        float* __restrict__ s1,
                                                        float* __restrict__ s2,
                                                        const int* __restrict__ src,
                                                        const int* __restrict__ dst,
                                                        int* __restrict__ bucket_cursor,
                                                        int* __restrict__ binned) {
    __shared__ unsigned short lB[3][8 * 2 * 64 * 8];   // 48 KB (gemm); binA aliases front 8KB

    if (blockIdx.x >= GEMM_BLOCKS) {
        // ---- binA role: bin edges by bucket (512-thread strides)
        int* cntL = (int*)&lB[0][0];
        int* baseL = cntL + BUCKETS;
        int t = threadIdx.x;
        for (int i = t; i < BUCKETS; i += 512) cntL[i] = 0;
        __syncthreads();
        size_t ebase = (size_t)(blockIdx.x - GEMM_BLOCKS) * A_EPC;

        for (int g = t; g < A_G4; g += 512) {
            int4 s4 = *(const int4*)(src + ebase + (size_t)g * 4);
#pragma unroll
            for (int j = 0; j < 4; ++j) {
                int s = (&s4.x)[j];
                atomicAdd(&cntL[s / BNODES], 1);
            }
        }
        __syncthreads();
        for (int i = t; i < BUCKETS; i += 512) {
            int c = cntL[i];
            baseL[i] = c ? atomicAdd(&bucket_cursor[i], c) : 0;
            cntL[i] = 0;
        }
        __syncthreads();
        for (int g = t; g < A_G4; g += 512) {
            int4 s4 = *(const int4*)(src + ebase + (size_t)g * 4);
            int4 d4 = *(const int4*)(dst + ebase + (size_t)g * 4);
#pragma unroll
            for (int j = 0; j < 4; ++j) {
                int s = (&s4.x)[j];
                int b = s / BNODES;
                int sl = s - b * BNODES;
                int pos = atomicAdd(&cntL[b], 1);
                int slot = baseL[b] + pos;
                if (slot < BCAP)
                    binned[(size_t)b * BCAP + slot] = (sl << 16) | (&d4.x)[j];
            }
        }
        return;
    }

    // ---- gemm role: tile 128x128, 8 waves (16 rows each), BK=64
    int bid = blockIdx.x;
    int t = threadIdx.x;
    int w = t >> 6;          // 0..7
    int L = t & 63;
    int m0 = bid * 128;

    int arow = m0 + w * 16 + (L & 15);
    int arow_c = arow < N_NODES ? arow : N_NODES - 1;   // clamp: loads unconditional
    int kq = (L >> 4) * 8;
    const float* arp = h + (size_t)arow_c * IN_FEAT + kq;

    f32x4 acc[8];
#pragma unroll
    for (int i = 0; i < 8; ++i) acc[i] = (f32x4){0.f, 0.f, 0.f, 0.f};

    auto stageB = [&](int slot, int k0) {
#pragma unroll
        for (int ksub = 0; ksub < 2; ++ksub) {
            const GLOBAL_AS unsigned short* g =
                (const GLOBAL_AS unsigned short*)(Wt + (size_t)(w * 16 + (L & 15)) * IN_FEAT +
                                                  (k0 + ksub * 32 + kq));
            LDS_AS unsigned short* lp = (LDS_AS unsigned short*)(&lB[slot][(w * 2 + ksub) * 512]);
            __builtin_amdgcn_global_load_lds((const GLOBAL_AS void*)g, (LDS_AS void*)lp, 16, 0, 0);
        }
    };
    auto loadA = [&](int step, float4 out[4]) {
        const float* p = arp + step * 64;
        out[0] = *(const float4*)(p);
        out[1] = *(const float4*)(p + 4);
        out[2] = *(const float4*)(p + 32);
        out[3] = *(const float4*)(p + 36);
    };
    auto convA = [&](const float4 a[4], short8& f0, short8& f1) {
        short8 v;
        v[0] = (short)f2bf(a[0].x); v[1] = (short)f2bf(a[0].y);
        v[2] = (short)f2bf(a[0].z); v[3] = (short)f2bf(a[0].w);
        v[4] = (short)f2bf(a[1].x); v[5] = (short)f2bf(a[1].y);
        v[6] = (short)f2bf(a[1].z); v[7] = (short)f2bf(a[1].w);
        f0 = v;
        v[0] = (short)f2bf(a[2].x); v[1] = (short)f2bf(a[2].y);
        v[2] = (short)f2bf(a[2].z); v[3] = (short)f2bf(a[2].w);
        v[4] = (short)f2bf(a[3].x); v[5] = (short)f2bf(a[3].y);
        v[6] = (short)f2bf(a[3].z); v[7] = (short)f2bf(a[3].w);
        f1 = v;
    };

    float4 avA[4], avB[4], avC[4];
#pragma unroll
    for (int q = 0; q < 4; ++q) avC[q] = make_float4(0.f, 0.f, 0.f, 0.f);

    stageB(0, 0);
    asm volatile("" ::: "memory");   // pin: stage(0) oldest in vmcnt order
    stageB(1, 64);
    loadA(0, avA);
    loadA(1, avB);
    asm volatile("s_waitcnt vmcnt(10)" ::: "memory");
    __builtin_amdgcn_s_barrier();

#pragma unroll
    for (int it = 0; it < 8; ++it) {
        if (it < 6) {
            stageB((it + 2) % 3, (it + 2) * 64);   // 2 VMEM
            loadA(it + 2, avC);                    // 4 VMEM
        }

        short8 af0, af1;
        convA(avA, af0, af1);

        const int buf = it % 3;
#pragma unroll
        for (int nb = 0; nb < 8; ++nb) {
            short8 bf = *(const short8*)(&lB[buf][((nb * 2 + 0) * 64 + L) * 8]);
            acc[nb] = __builtin_amdgcn_mfma_f32_16x16x32_bf16(af0, bf, acc[nb], 0, 0, 0);
        }
#pragma unroll
        for (int nb = 0; nb < 8; ++nb) {
            short8 bf = *(const short8*)(&lB[buf][((nb * 2 + 1) * 64 + L) * 8]);
            acc[nb] = __builtin_amdgcn_mfma_f32_16x16x32_bf16(af1, bf, acc[nb], 0, 0, 0);
        }

#pragma unroll
        for (int q = 0; q < 4; ++q) { avA[q] = avB[q]; avB[q] = avC[q]; }

        if (it < 6) {
            asm volatile("s_waitcnt vmcnt(6)" ::: "memory");
            __builtin_amdgcn_s_barrier();
        } else if (it == 6) {
            asm volatile("s_waitcnt vmcnt(0)" ::: "memory");
            __builtin_amdgcn_s_barrier();
        }
    }

    int col0 = L & 15;
    int rbase = m0 + w * 16 + (L >> 4) * 4;

    float a1c[8], a2c[8];
#pragma unroll
    for (int nb = 0; nb < 8; ++nb) {
        a1c[nb] = a_vec[nb * 16 + col0];
        a2c[nb] = a_vec[128 + nb * 16 + col0];
    }

#pragma unroll
    for (int r = 0; r < 4; ++r) {
        int row = rbase + r;
        bool ok = row < N_NODES;
        float p1 = 0.f, p2 = 0.f;
        if (ok) {
            unsigned short* orow = Whb + (size_t)row * OUT_FEAT;
#pragma unroll
            for (int nb = 0; nb < 8; ++nb) {
                float v = acc[nb][r];
                orow[nb * 16 + col0] = f2bf(v);
                p1 = fmaf(v, a1c[nb], p1);
                p2 = fmaf(v, a2c[nb], p2);
            }
        }
#pragma unroll
        for (int off = 8; off > 0; off >>= 1) {
            p1 += __shfl_xor(p1, off, 64);
            p2 += __shfl_xor(p2, off, 64);
        }
        if (ok && col0 == 0) {
            s1[row] = p1;
            s2[row] = p2;
        }
    }
}

// ---------------- K3: fused {binB scatter -> LDS CSR, node softmax+agg} ----
// v4: 1000 buckets x 50 nodes, one 512-thread block per bucket. vs round 12:
// no double-scan (each block scans its own ~1600-entry list, was 2x4000),
// balanced grid (~3.9 blocks/CU, ~31 waves/CU), 13KB LDS CSR.
// Phase-2 FMA loop: u32 bf16-pair unpack + float2 elementwise_fma
// (-> v_pk_fma_f32, full-rate 2xFP32) — numerically identical to 2 fmaf.

__global__ __launch_bounds__(512) void binB_node_kernel(const unsigned short* __restrict__ Whb,
                                                        const float* __restrict__ s1,
                                                        const float* __restrict__ s2,
                                                        const int* __restrict__ bucket_cursor,
                                                        const int* __restrict__ binned,
                                                        float* __restrict__ out) {
    __shared__ int cL[BNODES];                                // 200 B
    __shared__ unsigned short csrL[BNODES * PAD_DEG];         // 12800 B
    int b = blockIdx.x;
    int t = threadIdx.x;
    int n0 = b * BNODES;

    // ---- phase 1: bucket -> LDS csr
    if (t < BNODES) cL[t] = 0;
    __syncthreads();
    int m = min(bucket_cursor[b], BCAP);
    const int* bp = binned + (size_t)b * BCAP;
    for (int i = t; i < m; i += 512) {
        int p = bp[i];
        int sl = p >> 16;
        int d = p & 0xFFFF;
        int pos = atomicAdd(&cL[sl], 1);
        if (pos < PAD_DEG) csrL[sl * PAD_DEG + pos] = (unsigned short)d;
    }
    __syncthreads();

    // ---- phase 2: per-node softmax + aggregation (wave w: nodes w, w+8, ...)
    int lane = t & 63;
    int w = t >> 6;          // 0..7
    int g = lane >> 4;
    int fo = lane & 15;

    for (int sl = w; sl < BNODES; sl += 8) {
        int n = n0 + sl;
        int deg = min(cL[sl], PAD_DEG);
        const unsigned short* crow = &csrL[sl * PAD_DEG];

        f32x2 acc2[4];
#pragma unroll
        for (int q = 0; q < 4; ++q) acc2[q] = (f32x2){0.f, 0.f};
        float inv = 0.f;

        if (deg > 0) {
            float s1n = s1[n];
            int d0 = 0, d1 = 0;
            float ex0 = 0.f, ex1 = 0.f;
            if (lane < deg) {
                d0 = crow[lane];
                float ev = s1n + s2[d0];
                ev = ev >= 0.f ? ev : NEG_SLOPE * ev;
                ex0 = __expf(ev * INV_TEMP);
            }
            if (lane + 64 < deg) {
                d1 = crow[lane + 64];
                float ev = s1n + s2[d1];
                ev = ev >= 0.f ? ev : NEG_SLOPE * ev;
                ex1 = __expf(ev * INV_TEMP);
            }
            float denom = ex0 + ex1;
#pragma unroll
            for (int off = 32; off > 0; off >>= 1) denom += __shfl_xor(denom, off, 64);
            inv = 1.0f / denom;

#pragma unroll 2
            for (int jj = 0; jj < deg; jj += 8) {
                int e0 = jj + g;
                int e1 = jj + 4 + g;
                bool hi0 = jj >= 64;                 // wave-uniform
                bool hi1 = (jj + 4) >= 64;           // wave-uniform
                float p0 = __shfl(hi0 ? ex1 : ex0, e0 & 63, 64);
                int dd0 = __shfl(hi0 ? d1 : d0, e0 & 63, 64);
                float p1 = __shfl(hi1 ? ex1 : ex0, e1 & 63, 64);
                int dd1 = __shfl(hi1 ? d1 : d0, e1 & 63, 64);
                uint4 r0 = *(const uint4*)(Whb + (size_t)dd0 * OUT_FEAT + fo * 8);
                uint4 r1 = *(const uint4*)(Whb + (size_t)dd1 * OUT_FEAT + fo * 8);
                f32x2 pp0 = (f32x2){p0, p0};
                f32x2 pp1 = (f32x2){p1, p1};
#pragma unroll
                for (int q = 0; q < 4; ++q) {
                    unsigned int u = (&r0.x)[q];
                    f32x2 v;
                    v[0] = __uint_as_float(u << 16);
                    v[1] = __uint_as_float(u & 0xFFFF0000u);
                    acc2[q] = __builtin_elementwise_fma(pp0, v, acc2[q]);
                }
#pragma unroll
                for (int q = 0; q < 4; ++q) {
                    unsigned int u = (&r1.x)[q];
                    f32x2 v;
                    v[0] = __uint_as_float(u << 16);
                    v[1] = __uint_as_float(u & 0xFFFF0000u);
                    acc2[q] = __builtin_elementwise_fma(pp1, v, acc2[q]);
                }
            }
        }

        float accv[8];
#pragma unroll
        for (int q = 0; q < 4; ++q) {
            accv[2 * q] = acc2[q][0];
            accv[2 * q + 1] = acc2[q][1];
        }
        if (deg > 0) {
#pragma unroll
            for (int f = 0; f < 8; ++f) {
                accv[f] += __shfl_xor(accv[f], 16, 64);
                accv[f] += __shfl_xor(accv[f], 32, 64);
            }
        }

        if (g == 0) {
            float* orow = out + (size_t)n * OUT_FEAT + fo * 8;
            float4 o0, o1;
            o0.x = fmaxf(accv[0] * inv, 0.f); o0.y = fmaxf(accv[1] * inv, 0.f);
            o0.z = fmaxf(accv[2] * inv, 0.f); o0.w = fmaxf(accv[3] * inv, 0.f);
            o1.x = fmaxf(accv[4] * inv, 0.f); o1.y = fmaxf(accv[5] * inv, 0.f);
            o1.z = fmaxf(accv[6] * inv, 0.f); o1.w = fmaxf(accv[7] * inv, 0.f);
            *(float4*)(orow) = o0;
            *(float4*)(orow + 4) = o1;
        }
    }
}

// ---------------- launch ----------------

extern "C" void kernel_launch(void* const* d_in, const int* in_sizes, int n_in,
                              void* d_out, int out_size, void* d_ws, size_t ws_size,
                              hipStream_t stream) {
    const float* h = (const float*)d_in[0];
    const float* W = (const float*)d_in[1];
    const float* a = (const float*)d_in[2];
    const int* edge = (const int*)d_in[3];
    const int* src = edge;
    const int* dst = edge + N_EDGES;
    float* out = (float*)d_out;

    char* ws = (char*)d_ws;
    size_t off = 0;
    auto alloc = [&](size_t bytes) -> void* {
        void* p = ws + off;
        off = (off + bytes + 255) & ~(size_t)255;
        return p;
    };
    unsigned short* Whb = (unsigned short*)alloc((size_t)N_NODES * OUT_FEAT * sizeof(unsigned short));
    float* s1 = (float*)alloc((size_t)N_NODES * sizeof(float));
    float* s2 = (float*)alloc((size_t)N_NODES * sizeof(float));
    unsigned short* Wt = (unsigned short*)alloc((size_t)IN_FEAT * OUT_FEAT * sizeof(unsigned short));
    int* bucket_cursor = (int*)alloc((size_t)BUCKETS * sizeof(int));
    int* binned = (int*)alloc((size_t)BUCKETS * BCAP * sizeof(int));

    convw_kernel<<<CONV_BLOCKS, 256, 0, stream>>>(W, Wt, bucket_cursor);
    gemm_binA_kernel<<<GEMM_BLOCKS + A_BLOCKS, 512, 0, stream>>>(h, Wt, a, Whb, s1, s2,
                                                                 src, dst, bucket_cursor, binned);
    binB_node_kernel<<<BUCKETS, 512, 0, stream>>>(Whb, s1, s2, bucket_cursor, binned, out);
}